// Round 7
// baseline (644.445 us; speedup 1.0000x reference)
//
#include <hip/hip_runtime.h>

typedef __attribute__((ext_vector_type(8))) short bf16x8;   // 8 bf16 = 4 VGPRs
typedef __attribute__((ext_vector_type(4))) float f32x4;    // MFMA C/D

__device__ __forceinline__ float bf2f(unsigned short u){
    unsigned int v = ((unsigned int)u) << 16;
    return __builtin_bit_cast(float, v);
}
__device__ __forceinline__ unsigned short f2bf(float f){
    unsigned int u = __builtin_bit_cast(unsigned int, f);
    u += 0x7FFFu + ((u >> 16) & 1u);   // RTNE (no NaN inputs here)
    return (unsigned short)(u >> 16);
}

// ---- prep: W (K x 256) fp32 -> Wt (256 x K) bf16 (transposed) ----
__global__ void prep_wt(const float* __restrict__ W, unsigned short* __restrict__ Wt, int K){
    int k = blockIdx.x;
    int j = threadIdx.x;
    Wt[(size_t)j * K + k] = f2bf(W[(size_t)k * 256 + j]);
}

// ---- prep: x (b,m,d) fp32 -> Xt[b][d][m] bf16 ----
__global__ void prep_x(const float* __restrict__ x, unsigned short* __restrict__ Xt){
    int b = blockIdx.x;
    int t = threadIdx.x;
    #pragma unroll
    for (int it = 0; it < 8; it++){
        int o = it * 256 + t;          // o = d*32 + m
        int d = o >> 5, m = o & 31;
        Xt[(size_t)b * 2048 + o] = f2bf(x[(size_t)b * 2048 + m * 64 + d]);
    }
}

__global__ void init_out(float* __restrict__ out, const float* __restrict__ fcb){
    int i = blockIdx.x * 256 + threadIdx.x;
    if (i < 1024) out[i] = fcb[0];
}

// ---- fused CIN stage: Z-free fold, 8 waves = 4 j-waves x 2 c-groups ----
// Y[j][c] = sum_m x[c][m] * (sum_s W-frag(m*SB+s) MFMA h-frag(s)).
// Per wave: j=64 (jt 0..3), c=64 (ct 0..3, c = cg*64 + ct*16 + li).
// tmp[4][4] = AGPR MFMA C-chain over s; fold acc += xv*tmp once per m (16
// FMA/kt amortized). Bh[SB][4] = ALL h-fragments this lane ever needs,
// hoisted ONCE -> zero LDS reads & zero build-VALU in main loop; no barriers.
// Regs: acc 64 + tmp 64 + Bh 64 + Acur/Anx 32 + misc ~14 => ~238 <= 256
// -> 2 waves/SIMD via __launch_bounds__(512, 2).
template<int NN, int KTOT, int JX, bool HAS_HOUT>
__global__ __launch_bounds__(512, 2) void cin_stage(
    const unsigned short* __restrict__ Xt,
    const unsigned short* __restrict__ Hin,
    const unsigned short* __restrict__ Wt,
    const float* __restrict__ bias,
    const float* __restrict__ fcW,      // pre-offset for this layer
    unsigned short* __restrict__ Hout,  // [b][d][n] bf16, n in [0,128); null if !HAS_HOUT
    float* __restrict__ out)
{
    constexpr int SB  = NN / 32;                // kt per m-group
    constexpr int KT  = KTOT / 32;
    constexpr int XTS = 136;                    // Xlt row stride (shorts)
    constexpr int HS  = (NN == 32) ? 40 : 136;  // Hl row stride

    __shared__ unsigned short smem[21760];      // 43520 B
    unsigned short* const Xlt = smem;                  // [32][136] transposed x, 8704 B
    unsigned short* const Hl  = smem + 4352;           // [128][HS]
    unsigned short* const Yl  = smem + 4352;           // epilogue overlay [n:128][c pad 136]

    const int t    = threadIdx.x;
    const int lane = t & 63;
    const int w    = t >> 6;        // 0..7
    const int wj   = w & 3;         // j-group: j in [64*wj, 64*wj+64)
    const int cg   = w >> 2;        // c-group: c in [64*cg, 64*cg+64)
    const int li   = lane & 15;
    const int lq   = lane >> 4;
    const int cgo  = cg << 6;
    const int bpair = blockIdx.x;

    // ---- one-time staging: x transposed into Xlt; h (or x row-major) into Hl ----
    {
        const int c  = t >> 2;                  // 0..127
        const int b  = bpair * 2 + (c >> 6);
        const int d  = c & 63;
        const int mh = (t & 3) << 3;            // 0,8,16,24
        uint4 xq = *(const uint4*)(Xt + ((size_t)b << 11) + (d << 5) + mh);
        const unsigned short* xs = (const unsigned short*)&xq;
        #pragma unroll
        for (int q = 0; q < 8; q++) Xlt[(mh + q) * XTS + c] = xs[q];
        if (NN == 32){
            // stage 0: h == x, row-major [c][40]
            *(uint4*)(Hl + c * HS + mh) = xq;
        } else {
            const int nh = (t & 3) << 5;        // 0,32,64,96
            const uint4* hsrc = (const uint4*)(Hin + (size_t)((b << 6) + d) * 128 + nh);
            #pragma unroll
            for (int q = 0; q < 4; q++){
                uint4 hv = hsrc[q];
                *(uint4*)(Hl + c * HS + nh + q * 8) = hv;
            }
        }
    }
    __syncthreads();

    // hoist ALL h fragments this lane needs (SB*4 b128) -- once per kernel
    bf16x8 Bh[SB][4];
    #pragma unroll
    for (int s = 0; s < SB; s++)
        #pragma unroll
        for (int ct = 0; ct < 4; ct++)
            Bh[s][ct] = *(const bf16x8*)(Hl + (cgo + (ct << 4) + li) * HS + (s << 5) + (lq << 3));

    // A-fragments: lane reads Wt[j = wj*64 + jt*16 + li][kt*32 + lq*8 .. +8)
    const unsigned short* wbase = Wt + (size_t)((wj << 6) + li) * KTOT + (lq << 3);
    auto loadA = [&](int kt, bf16x8* A){
        const unsigned short* wk = wbase + (kt << 5);
        #pragma unroll
        for (int jt = 0; jt < 4; jt++)
            A[jt] = *(const bf16x8*)(wk + (size_t)jt * 16 * KTOT);
    };

    f32x4 acc[4][4];
    #pragma unroll
    for (int jt = 0; jt < 4; jt++)
        #pragma unroll
        for (int ct = 0; ct < 4; ct++)
            acc[jt][ct] = (f32x4){0.f, 0.f, 0.f, 0.f};

    const f32x4 fzero = (f32x4){0.f, 0.f, 0.f, 0.f};

    bf16x8 Acur[4];
    loadA(0, Acur);

    for (int m = 0; m < 32; m++){
        // xv issued here, consumed only after the s-loop's 16*SB MFMAs: latency-free
        float xv[4];
        #pragma unroll
        for (int ct = 0; ct < 4; ct++)
            xv[ct] = bf2f(Xlt[m * XTS + cgo + (ct << 4) + li]);   // broadcast, conflict-free

        f32x4 tmp[4][4];   // MFMA-only C-chain -> AGPRs
        #pragma unroll
        for (int s = 0; s < SB; s++){
            const int kt = m * SB + s;
            int ktn = kt + 1; if (ktn >= KT) ktn = KT - 1;
            bf16x8 Anx[4];
            loadA(ktn, Anx);                 // prefetch next kt's W (L2-resident)
            #pragma unroll
            for (int ct = 0; ct < 4; ct++)
                #pragma unroll
                for (int jt = 0; jt < 4; jt++)
                    tmp[jt][ct] = __builtin_amdgcn_mfma_f32_16x16x32_bf16(
                        Acur[jt], Bh[s][ct], (s == 0) ? fzero : tmp[jt][ct], 0, 0, 0);
            #pragma unroll
            for (int jt = 0; jt < 4; jt++) Acur[jt] = Anx[jt];
        }

        // fold once per m: acc += xv * tmp
        #pragma unroll
        for (int jt = 0; jt < 4; jt++)
            #pragma unroll
            for (int ct = 0; ct < 4; ct++)
                #pragma unroll
                for (int r = 0; r < 4; r++)
                    acc[jt][ct][r] += xv[ct] * tmp[jt][ct][r];
    }

    if (HAS_HOUT) __syncthreads();   // Yl overlays Hl: all waves done reading

    // epilogue: bias + relu; fc partial sums; stage h-half into Yl
    float pfc = 0.f;
    #pragma unroll
    for (int jt = 0; jt < 4; jt++){
        const int jb = (wj << 6) + (jt << 4) + (lq << 2);
        float bv[4], fv[4];
        #pragma unroll
        for (int r = 0; r < 4; r++){
            int j = jb + r;
            bv[r] = bias[j];
            fv[r] = (j < JX) ? fcW[j] : 0.f;
        }
        #pragma unroll
        for (int ct = 0; ct < 4; ct++){
            f32x4 f = acc[jt][ct];
            int c = cgo + (ct << 4) + li;
            #pragma unroll
            for (int r = 0; r < 4; r++){
                float y = f[r] + bv[r];
                y = y > 0.f ? y : 0.f;
                pfc += fv[r] * y;
                if (HAS_HOUT){
                    int j = jb + r;
                    if (j >= 128)
                        Yl[(j - 128) * 136 + c] = f2bf(y);
                }
            }
        }
    }
    #pragma unroll
    for (int off = 32; off; off >>= 1)
        pfc += __shfl_xor(pfc, off, 64);
    if (lane == 0)
        atomicAdd(out + bpair * 2 + cg, pfc);

    if (HAS_HOUT){
        __syncthreads();
        // cooperative store: Hout[(bpair*128 + c)*128 + n] = Yl[n][c]
        const int c  = t >> 2;
        const int nh = (t & 3) << 5;           // 32 shorts per thread
        unsigned short* gdst = Hout + (size_t)(bpair * 128 + c) * 128 + nh;
        #pragma unroll
        for (int i8 = 0; i8 < 4; i8++){
            uint4 tv;
            unsigned short* tmp2 = (unsigned short*)&tv;
            #pragma unroll
            for (int q = 0; q < 8; q++)
                tmp2[q] = Yl[(nh + i8 * 8 + q) * 136 + c];
            *(uint4*)(gdst + i8 * 8) = tv;
        }
    }
}

extern "C" void kernel_launch(void* const* d_in, const int* in_sizes, int n_in,
                              void* d_out, int out_size, void* d_ws, size_t ws_size,
                              hipStream_t stream){
    const float* x   = (const float*)d_in[0];
    const float* W0  = (const float*)d_in[1];
    const float* b0  = (const float*)d_in[2];
    const float* W1  = (const float*)d_in[3];
    const float* b1  = (const float*)d_in[4];
    const float* W2  = (const float*)d_in[5];
    const float* b2  = (const float*)d_in[6];
    const float* fcW = (const float*)d_in[7];
    const float* fcb = (const float*)d_in[8];
    float* out = (float*)d_out;

    char* ws = (char*)d_ws;
    unsigned short* Xt  = (unsigned short*)(ws);             // 4 MB
    unsigned short* Wt0 = (unsigned short*)(ws + 4194304);   // 512 KB
    unsigned short* Wt1 = (unsigned short*)(ws + 4718592);   // 2 MB
    unsigned short* Wt2 = (unsigned short*)(ws + 6815744);   // 2 MB
    unsigned short* H0  = (unsigned short*)(ws + 8912896);   // 16 MB
    unsigned short* H1  = (unsigned short*)(ws + 25690112);  // 16 MB (end 42467328)

    prep_wt<<<1024, 256, 0, stream>>>(W0, Wt0, 1024);
    prep_wt<<<4096, 256, 0, stream>>>(W1, Wt1, 4096);
    prep_wt<<<4096, 256, 0, stream>>>(W2, Wt2, 4096);
    prep_x <<<1024, 256, 0, stream>>>(x, Xt);
    init_out<<<4, 256, 0, stream>>>(out, fcb);

    cin_stage< 32, 1024, 128, true ><<<512, 512, 0, stream>>>(Xt, Xt, Wt0, b0, fcW,       H0, out);
    cin_stage<128, 4096, 128, true ><<<512, 512, 0, stream>>>(Xt, H0, Wt1, b1, fcW + 128, H1, out);
    cin_stage<128, 4096, 256, false><<<512, 512, 0, stream>>>(Xt, H1, Wt2, b2, fcW + 256, nullptr, out);
}

// Round 8
// 395.907 us; speedup vs baseline: 1.6278x; 1.6278x over previous
//
#include <hip/hip_runtime.h>

typedef __attribute__((ext_vector_type(8))) short bf16x8;   // 8 bf16 = 4 VGPRs
typedef __attribute__((ext_vector_type(4))) float f32x4;    // MFMA C/D

__device__ __forceinline__ float bf2f(unsigned short u){
    unsigned int v = ((unsigned int)u) << 16;
    return __builtin_bit_cast(float, v);
}
__device__ __forceinline__ unsigned short f2bf(float f){
    unsigned int u = __builtin_bit_cast(unsigned int, f);
    u += 0x7FFFu + ((u >> 16) & 1u);   // RTNE (no NaN inputs here)
    return (unsigned short)(u >> 16);
}
// HW packed f32->bf16 RTNE (verified correct in rounds 3/6)
__device__ __forceinline__ unsigned int cvt_pk_bf16(float lo, float hi){
    unsigned int r;
    asm("v_cvt_pk_bf16_f32 %0, %1, %2" : "=v"(r) : "v"(lo), "v"(hi));
    return r;
}
// z = xf * (bf16 pair in u) -> packed bf16 pair
__device__ __forceinline__ unsigned int mulpack(unsigned int u, float xf){
    float flo = __builtin_bit_cast(float, u << 16);
    float fhi = __builtin_bit_cast(float, u & 0xffff0000u);
    return cvt_pk_bf16(xf * flo, xf * fhi);
}

// ---- prep: W (K x 256) fp32 -> Wt (256 x K) bf16, LDS-tiled transpose ----
__global__ void prep_wt(const float* __restrict__ W, unsigned short* __restrict__ Wt, int K){
    __shared__ float tile[64][65];
    const int k0 = blockIdx.x * 64;
    const int j0 = blockIdx.y * 64;
    const int t  = threadIdx.x;              // 256
    #pragma unroll
    for (int it = 0; it < 16; it++){
        int idx = it * 256 + t;              // 4096 elems
        int kr = idx >> 6, jc = idx & 63;
        tile[kr][jc] = W[(size_t)(k0 + kr) * 256 + j0 + jc];   // coalesced read
    }
    __syncthreads();
    #pragma unroll
    for (int it = 0; it < 2; it++){
        int idx = it * 256 + t;              // 512 vec-writes
        int jr = idx >> 3, kc = (idx & 7) << 3;
        uint4 tv;
        unsigned short* ts = (unsigned short*)&tv;
        #pragma unroll
        for (int q = 0; q < 8; q++)
            ts[q] = f2bf(tile[kc + q][jr]);
        *(uint4*)(Wt + (size_t)(j0 + jr) * K + k0 + kc) = tv;  // coalesced b128 write
    }
}

// ---- prep: x (b,m,d) fp32 -> Xt[b][d][m] bf16 ----
__global__ void prep_x(const float* __restrict__ x, unsigned short* __restrict__ Xt){
    int b = blockIdx.x;
    int t = threadIdx.x;
    #pragma unroll
    for (int it = 0; it < 8; it++){
        int o = it * 256 + t;          // o = d*32 + m
        int d = o >> 5, m = o & 31;
        Xt[(size_t)b * 2048 + o] = f2bf(x[(size_t)b * 2048 + m * 64 + d]);
    }
}

__global__ void init_out(float* __restrict__ out, const float* __restrict__ fcb){
    int i = blockIdx.x * 256 + threadIdx.x;
    if (i < 1024) out[i] = fcb[0];
}

// ---- fused CIN stage: cooperative per-m Z-tile build + pure-GEMM phases ----
// Y[j][c] = sum_m sum_n W[(m,n)][j] * (x[c][m]*h[c][n]).
// Per m: Zm[c][n] = x[c][m]*h[c][n] built COOPERATIVELY (each elem once,
// ~9us chip-wide VALU) into a double-buffered LDS tile; then SB kt's of pure
// MFMA with acc C-chained over ALL 128 kt (AGPR, no fold). ONE barrier per m.
// A-frags ping-pong at m granularity (issued ~2000cy before use -> L2 hidden;
// static parity via 2x-unrolled m loop). 8 waves = 8 j-groups (j32 each,
// c=128 shared) -> W read once per block (no c-duplication of L2 traffic).
// Regs: acc 64 AGPR + A 2x32 + B 2x32 + misc ~ 225 -> 2 waves/SIMD.
// LDS: Xl 10240 + Hl 34816 + Zm 2x34816 = 114688 B -> 1 block/CU.
template<int NN, int KTOT, int JX, bool HAS_HOUT>
__global__ __launch_bounds__(512, 2) void cin_stage(
    const unsigned short* __restrict__ Xt,
    const unsigned short* __restrict__ Hin,
    const unsigned short* __restrict__ Wt,
    const float* __restrict__ bias,
    const float* __restrict__ fcW,      // pre-offset for this layer
    unsigned short* __restrict__ Hout,  // [b][d][n] bf16, n in [0,128); null if !HAS_HOUT
    float* __restrict__ out)
{
    constexpr int SB  = NN / 32;                 // kt per m
    constexpr int XS  = 40;                      // Xl row stride (shorts)
    constexpr int ZS  = (NN == 32) ? 40 : 136;   // Zm / Hl row stride
    constexpr int XLSZ = 128 * XS;               // 5120 shorts
    constexpr int HLSZ = (NN == 32) ? 0 : 128 * ZS;
    constexpr int ZMSZ = 128 * ZS;
    constexpr int NEED = XLSZ + HLSZ + 2 * ZMSZ;
    constexpr int SMSZ = NEED > 17408 ? NEED : 17408;   // Yl overlay needs 128*136

    __shared__ unsigned short smem[SMSZ];
    unsigned short* const Xl  = smem;
    unsigned short* const Hl  = (NN == 32) ? smem : (smem + XLSZ);  // h == x for stage 0
    unsigned short* const Zm0 = smem + XLSZ + HLSZ;
    unsigned short* const Zm1 = Zm0 + ZMSZ;
    unsigned short* const Yl  = smem;            // epilogue overlay [n:128][c pad 136]

    const int t    = threadIdx.x;
    const int lane = t & 63;
    const int w    = t >> 6;        // 0..7 : j in [32w, 32w+32)
    const int li   = lane & 15;
    const int lq   = lane >> 4;
    const int bpair = blockIdx.x;

    // ---- one-time staging: x -> Xl row-major; h -> Hl row-major ----
    {
        const int c  = t >> 2;                  // 0..127
        const int b  = bpair * 2 + (c >> 6);
        const int d  = c & 63;
        const int mh = (t & 3) << 3;            // 8 shorts per thread
        uint4 xq = *(const uint4*)(Xt + ((size_t)b << 11) + (d << 5) + mh);
        *(uint4*)(Xl + c * XS + mh) = xq;
        if (NN == 128){
            const int nh = (t & 3) << 5;        // 32 shorts per thread
            const uint4* hsrc = (const uint4*)(Hin + (size_t)((b << 6) + d) * 128 + nh);
            #pragma unroll
            for (int q = 0; q < 4; q++){
                uint4 hv = hsrc[q];
                *(uint4*)(Hl + c * ZS + nh + q * 8) = hv;
            }
        }
    }

    // cooperative Zm build for one m: thread t owns (c = t>>2, n-quarter t&3)
    const int bc = t >> 2;
    const int bn0 = (t & 3) * (NN / 4);
    auto build = [&](int m, unsigned short* zdst){
        float xf = bf2f(Xl[bc * XS + m]);
        #pragma unroll
        for (int q8 = 0; q8 < NN / 32; q8++){
            uint4 hv = *(const uint4*)(Hl + bc * ZS + bn0 + q8 * 8);
            uint4 zv;
            zv.x = mulpack(hv.x, xf);
            zv.y = mulpack(hv.y, xf);
            zv.z = mulpack(hv.z, xf);
            zv.w = mulpack(hv.w, xf);
            *(uint4*)(zdst + bc * ZS + bn0 + q8 * 8) = zv;
        }
    };

    // A fragments: lane reads Wt[j = 32w + jt*16 + li][kt*32 + lq*8 .. +8)
    const unsigned short* wrow = Wt + (size_t)((w << 5) + li) * KTOT + (lq << 3);
    auto aload = [&](bf16x8 (&A)[2][SB], int mm){
        #pragma unroll
        for (int jt = 0; jt < 2; jt++)
            #pragma unroll
            for (int s = 0; s < SB; s++)
                A[jt][s] = *(const bf16x8*)(wrow + (size_t)jt * 16 * KTOT + (mm * SB + s) * 32);
    };

    f32x4 acc[2][8];   // pure MFMA C-chain over all 128 kt -> AGPRs
    #pragma unroll
    for (int jt = 0; jt < 2; jt++)
        #pragma unroll
        for (int ct = 0; ct < 8; ct++)
            acc[jt][ct] = (f32x4){0.f, 0.f, 0.f, 0.f};

    // pure-GEMM phase over Zm buffer zp with A-array Ar
    auto mfma_phase = [&](const unsigned short* zp, bf16x8 (&Ar)[2][SB]){
        bf16x8 Bf[2][8];
        #pragma unroll
        for (int ct = 0; ct < 8; ct++)
            Bf[0][ct] = *(const bf16x8*)(zp + ((ct << 4) + li) * ZS + (lq << 3));
        #pragma unroll
        for (int s = 0; s < SB; s++){
            if (s + 1 < SB){
                #pragma unroll
                for (int ct = 0; ct < 8; ct++)
                    Bf[(s + 1) & 1][ct] = *(const bf16x8*)(zp + ((ct << 4) + li) * ZS + ((s + 1) << 5) + (lq << 3));
            }
            #pragma unroll
            for (int ct = 0; ct < 8; ct++)
                #pragma unroll
                for (int jt = 0; jt < 2; jt++)
                    acc[jt][ct] = __builtin_amdgcn_mfma_f32_16x16x32_bf16(
                        Ar[jt][s], Bf[s & 1][ct], acc[jt][ct], 0, 0, 0);
        }
    };

    __syncthreads();                 // staging done
    bf16x8 Aa[2][SB], Ab[2][SB];
    build(0, Zm0);
    aload(Aa, 0);
    __syncthreads();                 // Zm0(m=0) ready

    for (int m = 0; m < 32; m += 2){
        // even phase: compute Zm0(m) with Aa; prep m+1
        aload(Ab, m + 1);                        // m+1 <= 31 always
        mfma_phase(Zm0, Aa);
        build(m + 1, Zm1);
        __syncthreads();
        // odd phase: compute Zm1(m+1) with Ab; prep m+2
        aload(Aa, (m + 2 < 32) ? m + 2 : 31);    // clamp (dup load, unused)
        mfma_phase(Zm1, Ab);
        if (m + 2 < 32) build(m + 2, Zm0);
        __syncthreads();
    }

    // epilogue: bias + relu; fc partial sums; stage h-half into Yl overlay
    float pfc0 = 0.f, pfc1 = 0.f;
    #pragma unroll
    for (int jt = 0; jt < 2; jt++){
        const int jb = (w << 5) + (jt << 4) + (lq << 2);
        float bv[4], fv[4];
        #pragma unroll
        for (int r = 0; r < 4; r++){
            int j = jb + r;
            bv[r] = bias[j];
            fv[r] = (j < JX) ? fcW[j] : 0.f;
        }
        #pragma unroll
        for (int ct = 0; ct < 8; ct++){
            f32x4 f = acc[jt][ct];
            int c = (ct << 4) + li;
            float ps = 0.f;
            #pragma unroll
            for (int r = 0; r < 4; r++){
                float y = f[r] + bv[r];
                y = y > 0.f ? y : 0.f;
                ps += fv[r] * y;
                if (HAS_HOUT){
                    int j = jb + r;
                    if (j >= 128)
                        Yl[(j - 128) * 136 + c] = f2bf(y);
                }
            }
            if (ct < 4) pfc0 += ps; else pfc1 += ps;
        }
    }
    #pragma unroll
    for (int off = 32; off; off >>= 1){
        pfc0 += __shfl_xor(pfc0, off, 64);
        pfc1 += __shfl_xor(pfc1, off, 64);
    }
    if (lane == 0){
        atomicAdd(out + bpair * 2 + 0, pfc0);
        atomicAdd(out + bpair * 2 + 1, pfc1);
    }

    if (HAS_HOUT){
        __syncthreads();
        // cooperative store: Hout[(bpair*128 + c)*128 + n] = Yl[n][c]
        const int c  = t >> 2;
        const int nh = (t & 3) << 5;           // 32 shorts per thread
        unsigned short* gdst = Hout + (size_t)(bpair * 128 + c) * 128 + nh;
        #pragma unroll
        for (int i8 = 0; i8 < 4; i8++){
            uint4 tv;
            unsigned short* tmp2 = (unsigned short*)&tv;
            #pragma unroll
            for (int q = 0; q < 8; q++)
                tmp2[q] = Yl[(nh + i8 * 8 + q) * 136 + c];
            *(uint4*)(gdst + i8 * 8) = tv;
        }
    }
}

extern "C" void kernel_launch(void* const* d_in, const int* in_sizes, int n_in,
                              void* d_out, int out_size, void* d_ws, size_t ws_size,
                              hipStream_t stream){
    const float* x   = (const float*)d_in[0];
    const float* W0  = (const float*)d_in[1];
    const float* b0  = (const float*)d_in[2];
    const float* W1  = (const float*)d_in[3];
    const float* b1  = (const float*)d_in[4];
    const float* W2  = (const float*)d_in[5];
    const float* b2  = (const float*)d_in[6];
    const float* fcW = (const float*)d_in[7];
    const float* fcb = (const float*)d_in[8];
    float* out = (float*)d_out;

    char* ws = (char*)d_ws;
    unsigned short* Xt  = (unsigned short*)(ws);             // 4 MB
    unsigned short* Wt0 = (unsigned short*)(ws + 4194304);   // 512 KB
    unsigned short* Wt1 = (unsigned short*)(ws + 4718592);   // 2 MB
    unsigned short* Wt2 = (unsigned short*)(ws + 6815744);   // 2 MB
    unsigned short* H0  = (unsigned short*)(ws + 8912896);   // 16 MB
    unsigned short* H1  = (unsigned short*)(ws + 25690112);  // 16 MB (end 42467328)

    prep_wt<<<dim3(16, 4), 256, 0, stream>>>(W0, Wt0, 1024);
    prep_wt<<<dim3(64, 4), 256, 0, stream>>>(W1, Wt1, 4096);
    prep_wt<<<dim3(64, 4), 256, 0, stream>>>(W2, Wt2, 4096);
    prep_x <<<1024, 256, 0, stream>>>(x, Xt);
    init_out<<<4, 256, 0, stream>>>(out, fcb);

    cin_stage< 32, 1024, 128, true ><<<512, 512, 0, stream>>>(Xt, Xt, Wt0, b0, fcW,       H0, out);
    cin_stage<128, 4096, 128, true ><<<512, 512, 0, stream>>>(Xt, H0, Wt1, b1, fcW + 128, H1, out);
    cin_stage<128, 4096, 256, false><<<512, 512, 0, stream>>>(Xt, H1, Wt2, b2, fcW + 256, nullptr, out);
}